// Round 1
// baseline (399.609 us; speedup 1.0000x reference)
//
#include <hip/hip_runtime.h>
#include <math.h>

// I-BERT IntSoftmax, exact-numerics replication of the JAX reference.
// Shapes: x is (1,12,2048,2048) f32; rows = 24576 of length S=2048.

#define ROW_S 2048
#define MM_BLOCKS 1024

struct Scalars {
    double exp_sf_d;   // exp_sf cast to f64 (fixedpoint_mul divisor)
    double m_int;      // 31-bit mantissa (f64)
    double inv_pow;    // 2^(e-31) (exact power of two)
    float  sf;         // activation scale
    float  x0_int;     // floor(-0.6931/sf)
    float  b_int;      // floor(COEF1/sf)
    float  c_int;      // floor(COEF2/sf^2)
    float  thirty_x0;  // 30 * x0_int
    float  _pad[3];
};

__global__ __launch_bounds__(256) void k_minmax(const float* __restrict__ x,
                                                float* __restrict__ pmin,
                                                float* __restrict__ pmax,
                                                int n4) {
    __shared__ float smin[256], smax[256];
    const int tid = threadIdx.x;
    float vmin = INFINITY, vmax = -INFINITY;
    const float4* x4 = (const float4*)x;
    for (int i = blockIdx.x * 256 + tid; i < n4; i += MM_BLOCKS * 256) {
        float4 v = x4[i];
        vmin = fminf(vmin, fminf(fminf(v.x, v.y), fminf(v.z, v.w)));
        vmax = fmaxf(vmax, fmaxf(fmaxf(v.x, v.y), fmaxf(v.z, v.w)));
    }
    smin[tid] = vmin; smax[tid] = vmax;
    __syncthreads();
    for (int o = 128; o > 0; o >>= 1) {
        if (tid < o) {
            smin[tid] = fminf(smin[tid], smin[tid + o]);
            smax[tid] = fmaxf(smax[tid], smax[tid + o]);
        }
        __syncthreads();
    }
    if (tid == 0) { pmin[blockIdx.x] = smin[0]; pmax[blockIdx.x] = smax[0]; }
}

__global__ __launch_bounds__(256) void k_scalars(const float* __restrict__ pmin,
                                                 const float* __restrict__ pmax,
                                                 Scalars* __restrict__ sc) {
    __shared__ float smin[256], smax[256];
    const int tid = threadIdx.x;
    float vmin = INFINITY, vmax = -INFINITY;
    for (int i = tid; i < MM_BLOCKS; i += 256) {
        vmin = fminf(vmin, pmin[i]);
        vmax = fmaxf(vmax, pmax[i]);
    }
    smin[tid] = vmin; smax[tid] = vmax;
    __syncthreads();
    for (int o = 128; o > 0; o >>= 1) {
        if (tid < o) {
            smin[tid] = fminf(smin[tid], smin[tid + o]);
            smax[tid] = fmaxf(smax[tid], smax[tid + o]);
        }
        __syncthreads();
    }
    if (tid == 0) {
        const float xmin = smin[0], xmax = smax[0];
        // sym_scale(x.min, x.max, 16), all f32 like the reference
        const float sabs  = fmaxf(fabsf(xmin), fabsf(xmax));
        const float sf    = __fdiv_rn(fmaxf(sabs, 1e-8f), 32767.0f);
        const float x0i   = floorf(__fdiv_rn((float)(-0.6931), sf));
        const float sfsq  = __fmul_rn(sf, sf);
        const float b_int = floorf(__fdiv_rn((float)(0.96963238 / 0.35815147), sf));
        const float c_int = floorf(__fdiv_rn((float)(1.0 / 0.35815147), sfsq));
        const float exp_sf = __fdiv_rn(__fmul_rn((float)(0.35815147), sfsq), 1073741824.0f);
        // global max of exp_int is exactly c_int * 2^30 (every row's max element
        // hits r=0,q=0 => z=c_int); min>=0, so sym_scale uses this max.
        const float emax   = __fmul_rn(c_int, 1073741824.0f);   // exact pow2 scale
        const float act_sf = __fdiv_rn(fmaxf(emax, 1e-8f), 32767.0f);
        // fixedpoint_mul scalar part (f64, per reference)
        const float  nsf = __fdiv_rn(exp_sf, act_sf);  // f32 div, then cast (as in ref)
        const double ns  = (double)nsf;
        int E;
        (void)frexp(ns, &E);                 // e = floor(log2(ns)) + 1 == E, exactly
        const double m_int = rint(ldexp(ns, 31 - E));   // round((ns/2^e)*2^31), exact scaling
        sc->exp_sf_d  = (double)exp_sf;
        sc->m_int     = m_int;
        sc->inv_pow   = ldexp(1.0, E - 31);  // dividing by 2^(31-e) == multiplying by this (exact)
        sc->sf        = sf;
        sc->x0_int    = x0i;
        sc->b_int     = b_int;
        sc->c_int     = c_int;
        sc->thirty_x0 = __fmul_rn(30.0f, x0i);
    }
}

__global__ __launch_bounds__(256) void k_row(const float* __restrict__ x,
                                             float* __restrict__ out,
                                             const Scalars* __restrict__ scp) {
    const int tid = threadIdx.x;
    const size_t rowbase = (size_t)blockIdx.x * ROW_S;
    const float4* x4 = (const float4*)(x + rowbase);
    float4* o4 = (float4*)(out + rowbase);

    const Scalars sc = *scp;
    const float sf = sc.sf;

    // 8 elements per thread: two coalesced float4 loads
    const float4 va = x4[tid];
    const float4 vb = x4[tid + 256];
    float xv[8] = {va.x, va.y, va.z, va.w, vb.x, vb.y, vb.z, vb.w};

    float xi[8];
    float vmax = -INFINITY;
#pragma unroll
    for (int j = 0; j < 8; ++j) {
        // QuantAct(16): x_int = clip(rint(x/sf)); xi = (x_int*sf)/sf  (all f32, no FMA)
        float t = rintf(__fdiv_rn(xv[j], sf));
        t = fminf(fmaxf(t, -32768.0f), 32767.0f);
        t = __fmul_rn(t, sf);
        t = __fdiv_rn(t, sf);
        xi[j] = t;
        vmax = fmaxf(vmax, t);
    }

    __shared__ float red[256];
    red[tid] = vmax;
    __syncthreads();
    for (int o = 128; o > 0; o >>= 1) {
        if (tid < o) red[tid] = fmaxf(red[tid], red[tid + o]);
        __syncthreads();
    }
    const float ximax = red[0];
    __syncthreads();  // before reusing red[] for the sum

    float e16[8];
    float ssum = 0.0f;
#pragma unroll
    for (int j = 0; j < 8; ++j) {
        const float xs = __fsub_rn(xi[j], ximax);
        const float xm = fmaxf(xs, sc.thirty_x0);
        const float qf = floorf(__fdiv_rn(xm, sc.x0_int));
        const float r  = __fsub_rn(xm, __fmul_rn(sc.x0_int, qf));
        // z = r*(r+b)+c  -- MUST NOT contract to FMA (XLA CPU doesn't)
        const float z  = __fadd_rn(__fmul_rn(r, __fadd_rn(r, sc.b_int)), sc.c_int);
        const int   qi = (int)qf;                       // qf in [0,30]
        const float p2 = __int_as_float((157 - qi) << 23);  // exactly 2^(30-qi)
        const float ei = fmaxf(floorf(__fmul_rn(z, p2)), 0.0f);
        // fixedpoint_mul in f64 (reference runs this in double precision)
        const double zi = rint((double)ei / sc.exp_sf_d);
        double ov = rint(__dmul_rn(zi, sc.m_int) * sc.inv_pow);  // *2^(e-31) exact
        ov = fmin(fmax(ov, -32768.0), 32767.0);
        const float v = (float)ov;   // integer-valued, exact cast
        e16[j] = v;
        ssum += v;   // non-negative integers, total < 2^24 -> order-free exact
    }

    red[tid] = ssum;
    __syncthreads();
    for (int o = 128; o > 0; o >>= 1) {
        if (tid < o) red[tid] = red[tid] + red[tid + o];
        __syncthreads();
    }
    const float s = red[0];
    const float factor = floorf(__fdiv_rn(4294967296.0f, s));

    float ov[8];
#pragma unroll
    for (int j = 0; j < 8; ++j) {
        const float oi = floorf(__fdiv_rn(__fmul_rn(e16[j], factor), 16777216.0f));
        ov[j] = __fmul_rn(oi, 0.00390625f);  // * 2^-8, exact
    }
    o4[tid]       = make_float4(ov[0], ov[1], ov[2], ov[3]);
    o4[tid + 256] = make_float4(ov[4], ov[5], ov[6], ov[7]);
}

extern "C" void kernel_launch(void* const* d_in, const int* in_sizes, int n_in,
                              void* d_out, int out_size, void* d_ws, size_t ws_size,
                              hipStream_t stream) {
    const float* x = (const float*)d_in[0];
    float* out = (float*)d_out;
    const int n = in_sizes[0];          // 50331648
    const int rows = n / ROW_S;         // 24576

    Scalars* sc = (Scalars*)d_ws;
    float* pmin = (float*)((char*)d_ws + 64);
    float* pmax = pmin + MM_BLOCKS;

    k_minmax<<<MM_BLOCKS, 256, 0, stream>>>(x, pmin, pmax, n / 4);
    k_scalars<<<1, 256, 0, stream>>>(pmin, pmax, sc);
    k_row<<<rows, 256, 0, stream>>>(x, out, sc);
}

// Round 3
// 355.135 us; speedup vs baseline: 1.1252x; 1.1252x over previous
//
#include <hip/hip_runtime.h>
#include <math.h>

// I-BERT IntSoftmax, exact-numerics replication of the JAX reference.
// x: (1,12,2048,2048) f32; 24576 rows of S=2048.
// R3: R2 + fix nontemporal store to use native ext_vector_type.

#define ROW_S 2048
#define MM_BLOCKS 2048

typedef float floatx4 __attribute__((ext_vector_type(4)));

struct Scalars {
    double exp_sf_d;   // exp_sf (f64) — fixedpoint_mul divisor
    double inv_exp_sf; // RN(1/exp_sf_d), f64 (Markstein reciprocal)
    double m_int;      // 31-bit mantissa (f64)
    double inv_pow;    // 2^(e-31) exact
    float  sf;         // activation scale
    float  inv_sf;     // RN(1/sf)
    float  x0_int;     // floor(-0.6931/sf)
    float  inv_x0;     // RN(1/x0_int)
    float  b_int;      // floor(COEF1/sf)
    float  c_int;      // floor(COEF2/sf^2)
    float  thirty_x0;  // 30 * x0_int (exact)
    float  _pad;
};

// Markstein: with inv = RN(1/b), returns RN(a/b) bit-exactly.
__device__ __forceinline__ float div_rn(float a, float b, float inv) {
    const float q0 = __fmul_rn(a, inv);
    const float r  = __fmaf_rn(-b, q0, a);
    return __fmaf_rn(r, inv, q0);
}
__device__ __forceinline__ double ddiv_rn(double a, double b, double inv) {
    const double q0 = __dmul_rn(a, inv);
    const double r  = __fma_rn(-b, q0, a);
    return __fma_rn(r, inv, q0);
}

__global__ __launch_bounds__(256) void k_minmax(const float* __restrict__ x,
                                                float* __restrict__ pmin,
                                                float* __restrict__ pmax,
                                                int n4) {
    const int tid = threadIdx.x;
    float vmin = INFINITY, vmax = -INFINITY;
    const float4* x4 = (const float4*)x;
    for (int i = blockIdx.x * 256 + tid; i < n4; i += MM_BLOCKS * 256) {
        float4 v = x4[i];
        vmin = fminf(vmin, fminf(fminf(v.x, v.y), fminf(v.z, v.w)));
        vmax = fmaxf(vmax, fmaxf(fmaxf(v.x, v.y), fmaxf(v.z, v.w)));
    }
#pragma unroll
    for (int m = 32; m > 0; m >>= 1) {
        vmin = fminf(vmin, __shfl_xor(vmin, m));
        vmax = fmaxf(vmax, __shfl_xor(vmax, m));
    }
    __shared__ float smin[4], smax[4];
    const int wave = tid >> 6, lane = tid & 63;
    if (lane == 0) { smin[wave] = vmin; smax[wave] = vmax; }
    __syncthreads();
    if (tid == 0) {
        pmin[blockIdx.x] = fminf(fminf(smin[0], smin[1]), fminf(smin[2], smin[3]));
        pmax[blockIdx.x] = fmaxf(fmaxf(smax[0], smax[1]), fmaxf(smax[2], smax[3]));
    }
}

__global__ __launch_bounds__(256) void k_scalars(const float* __restrict__ pmin,
                                                 const float* __restrict__ pmax,
                                                 Scalars* __restrict__ sc) {
    const int tid = threadIdx.x;
    float vmin = INFINITY, vmax = -INFINITY;
    for (int i = tid; i < MM_BLOCKS; i += 256) {
        vmin = fminf(vmin, pmin[i]);
        vmax = fmaxf(vmax, pmax[i]);
    }
#pragma unroll
    for (int m = 32; m > 0; m >>= 1) {
        vmin = fminf(vmin, __shfl_xor(vmin, m));
        vmax = fmaxf(vmax, __shfl_xor(vmax, m));
    }
    __shared__ float smin[4], smax[4];
    const int wave = tid >> 6, lane = tid & 63;
    if (lane == 0) { smin[wave] = vmin; smax[wave] = vmax; }
    __syncthreads();
    if (tid == 0) {
        const float xmin = fminf(fminf(smin[0], smin[1]), fminf(smin[2], smin[3]));
        const float xmax = fmaxf(fmaxf(smax[0], smax[1]), fmaxf(smax[2], smax[3]));
        // sym_scale(x.min, x.max, 16), all f32 like the reference
        const float sabs  = fmaxf(fabsf(xmin), fabsf(xmax));
        const float sf    = __fdiv_rn(fmaxf(sabs, 1e-8f), 32767.0f);
        const float x0i   = floorf(__fdiv_rn((float)(-0.6931), sf));
        const float sfsq  = __fmul_rn(sf, sf);
        const float b_int = floorf(__fdiv_rn((float)(0.96963238 / 0.35815147), sf));
        const float c_int = floorf(__fdiv_rn((float)(1.0 / 0.35815147), sfsq));
        const float exp_sf = __fdiv_rn(__fmul_rn((float)(0.35815147), sfsq), 1073741824.0f);
        // global max of exp_int is exactly c_int * 2^30 (row-max element has
        // r=0,q=0 => z=c_int); min>=0, so sym_scale uses this max.
        const float emax   = __fmul_rn(c_int, 1073741824.0f);
        const float act_sf = __fdiv_rn(fmaxf(emax, 1e-8f), 32767.0f);
        // fixedpoint_mul scalar part (f64, per reference)
        const float  nsf = __fdiv_rn(exp_sf, act_sf);
        const double ns  = (double)nsf;
        int E;
        (void)frexp(ns, &E);                 // e = floor(log2(ns)) + 1 == E exactly
        const double m_int = rint(ldexp(ns, 31 - E));
        sc->exp_sf_d   = (double)exp_sf;
        sc->inv_exp_sf = 1.0 / (double)exp_sf;        // RN f64 reciprocal
        sc->m_int      = m_int;
        sc->inv_pow    = ldexp(1.0, E - 31);          // exact pow2
        sc->sf         = sf;
        sc->inv_sf     = __fdiv_rn(1.0f, sf);         // RN f32 reciprocal
        sc->x0_int     = x0i;
        sc->inv_x0     = __fdiv_rn(1.0f, x0i);        // RN f32 reciprocal
        sc->b_int      = b_int;
        sc->c_int      = c_int;
        sc->thirty_x0  = __fmul_rn(30.0f, x0i);       // exact (integer < 2^24)
    }
}

__global__ __launch_bounds__(256) void k_row(const float* __restrict__ x,
                                             float* __restrict__ out,
                                             const Scalars* __restrict__ scp) {
    const int tid = threadIdx.x;
    const size_t rowbase = (size_t)blockIdx.x * ROW_S;
    const float4* x4 = (const float4*)(x + rowbase);
    floatx4* o4 = (floatx4*)(out + rowbase);

    // issue global loads first, scalar struct load overlaps
    const float4 va = x4[tid];
    const float4 vb = x4[tid + 256];

    const Scalars sc = *scp;
    const float sf = sc.sf, inv_sf = sc.inv_sf;

    float xv[8] = {va.x, va.y, va.z, va.w, vb.x, vb.y, vb.z, vb.w};

    float xi[8];
    float vmax = -INFINITY;
#pragma unroll
    for (int j = 0; j < 8; ++j) {
        // QuantAct(16): x_int = clip(rint(x/sf)); xi = (x_int*sf)/sf (all RN, no FMA)
        float t = rintf(div_rn(xv[j], sf, inv_sf));
        t = fminf(fmaxf(t, -32768.0f), 32767.0f);
        t = __fmul_rn(t, sf);
        t = div_rn(t, sf, inv_sf);
        xi[j] = t;
        vmax = fmaxf(vmax, t);
    }

    // block max: wave butterfly + 4-slot LDS
    __shared__ float red[8];
    const int wave = tid >> 6, lane = tid & 63;
#pragma unroll
    for (int m = 32; m > 0; m >>= 1) vmax = fmaxf(vmax, __shfl_xor(vmax, m));
    if (lane == 0) red[wave] = vmax;
    __syncthreads();
    const float ximax = fmaxf(fmaxf(red[0], red[1]), fmaxf(red[2], red[3]));

    float e16[8];
    float ssum = 0.0f;
#pragma unroll
    for (int j = 0; j < 8; ++j) {
        const float xs = __fsub_rn(xi[j], ximax);
        const float xm = fmaxf(xs, sc.thirty_x0);
        const float qf = floorf(div_rn(xm, sc.x0_int, sc.inv_x0));
        const float r  = __fsub_rn(xm, __fmul_rn(sc.x0_int, qf));
        // z = r*(r+b)+c — must NOT contract to FMA (XLA CPU doesn't)
        const float z  = __fadd_rn(__fmul_rn(r, __fadd_rn(r, sc.b_int)), sc.c_int);
        const int   qi = (int)qf;                          // qf in [0,30]
        const float p2 = __int_as_float((157 - qi) << 23); // exactly 2^(30-qi)
        const float ei = fmaxf(floorf(__fmul_rn(z, p2)), 0.0f);
        // fixedpoint_mul in f64 (reference runs in double)
        const double a  = (double)ei;
        const double zi = rint(ddiv_rn(a, sc.exp_sf_d, sc.inv_exp_sf));
        double ov = rint(__dmul_rn(__dmul_rn(zi, sc.m_int), sc.inv_pow)); // *2^(e-31) exact
        ov = fmin(fmax(ov, -32768.0), 32767.0);
        const float v = (float)ov;   // integer-valued, exact
        e16[j] = v;
        ssum += v;   // non-negative ints, row sum < 2^24 -> order-free exact
    }

    // block sum: wave butterfly + 4-slot LDS (distinct slots: one extra barrier only)
#pragma unroll
    for (int m = 32; m > 0; m >>= 1) ssum += __shfl_xor(ssum, m);
    if (lane == 0) red[4 + wave] = ssum;
    __syncthreads();
    const float s = ((red[4] + red[5]) + (red[6] + red[7]));
    const float factor = floorf(__fdiv_rn(4294967296.0f, s));

    float ov[8];
#pragma unroll
    for (int j = 0; j < 8; ++j) {
        // /2^24 == *2^-24 exactly (pow2), then *2^-8 exact
        const float oi = floorf(__fmul_rn(__fmul_rn(e16[j], factor), 5.9604644775390625e-8f));
        ov[j] = __fmul_rn(oi, 0.00390625f);
    }
    floatx4 w0 = {ov[0], ov[1], ov[2], ov[3]};
    floatx4 w1 = {ov[4], ov[5], ov[6], ov[7]};
    __builtin_nontemporal_store(w0, &o4[tid]);
    __builtin_nontemporal_store(w1, &o4[tid + 256]);
}

extern "C" void kernel_launch(void* const* d_in, const int* in_sizes, int n_in,
                              void* d_out, int out_size, void* d_ws, size_t ws_size,
                              hipStream_t stream) {
    const float* x = (const float*)d_in[0];
    float* out = (float*)d_out;
    const int n = in_sizes[0];          // 50331648
    const int rows = n / ROW_S;         // 24576

    Scalars* sc = (Scalars*)d_ws;
    float* pmin = (float*)((char*)d_ws + 256);
    float* pmax = pmin + MM_BLOCKS;

    k_minmax<<<MM_BLOCKS, 256, 0, stream>>>(x, pmin, pmax, n / 4);
    k_scalars<<<1, 256, 0, stream>>>(pmin, pmax, sc);
    k_row<<<rows, 256, 0, stream>>>(x, out, sc);
}